// Round 7
// baseline (132.169 us; speedup 1.0000x reference)
//
#include <hip/hip_runtime.h>
#include <math.h>

#define PI_F      3.14159265358979323846f
#define TWO_PI_F  6.28318530717958647692f
#define INV_2PI_F 0.15915494309189533577f

typedef float v2 __attribute__((ext_vector_type(2)));

// ---- scalar raw-instruction helpers ----
__device__ __forceinline__ float fsqrt(float x)  { return __builtin_amdgcn_sqrtf(x); }
__device__ __forceinline__ float frcp(float x)   { return __builtin_amdgcn_rcpf(x); }
__device__ __forceinline__ float frsq(float x)   { return __builtin_amdgcn_rsqf(x); }
__device__ __forceinline__ float fexp2(float x)  { return __builtin_amdgcn_exp2f(x); }
__device__ __forceinline__ float flog2(float x)  { return __builtin_amdgcn_logf(x); }
__device__ __forceinline__ float fsin(float x)   { return __builtin_amdgcn_sinf(x * INV_2PI_F); }
__device__ __forceinline__ float fcos(float x)   { return __builtin_amdgcn_cosf(x * INV_2PI_F); }

// ---- v2 helpers: elementwise; trans ops stay scalar per component ----
__device__ __forceinline__ v2 V(float s){ v2 r; r.x = s; r.y = s; return r; }
__device__ __forceinline__ v2 V2(float a, float b){ v2 r; r.x = a; r.y = b; return r; }
#if __has_builtin(__builtin_elementwise_fma)
__device__ __forceinline__ v2 vfma(v2 a, v2 b, v2 c){ return __builtin_elementwise_fma(a, b, c); }
#else
__device__ __forceinline__ v2 vfma(v2 a, v2 b, v2 c){ v2 r; r.x=__fmaf_rn(a.x,b.x,c.x); r.y=__fmaf_rn(a.y,b.y,c.y); return r; }
#endif
__device__ __forceinline__ v2 vmax0(v2 a){ v2 r; r.x=fmaxf(a.x,0.0f); r.y=fmaxf(a.y,0.0f); return r; }
__device__ __forceinline__ v2 vsqrt(v2 x){ v2 r; r.x=fsqrt(x.x); r.y=fsqrt(x.y); return r; }
__device__ __forceinline__ v2 vrcp (v2 x){ v2 r; r.x=frcp(x.x);  r.y=frcp(x.y);  return r; }
__device__ __forceinline__ v2 vrsq (v2 x){ v2 r; r.x=frsq(x.x);  r.y=frsq(x.y);  return r; }
__device__ __forceinline__ v2 vexp2(v2 x){ v2 r; r.x=fexp2(x.x); r.y=fexp2(x.y); return r; }
__device__ __forceinline__ v2 vsinr(v2 x){ v2 r; r.x=fsin(x.x); r.y=fsin(x.y); return r; }
__device__ __forceinline__ v2 vcosr(v2 x){ v2 r; r.x=fcos(x.x); r.y=fcos(x.y); return r; }

// ============================================================================
// UPSTREAM — PACKED v2 (compiler-vectorized; NO inline asm). Every per-element
// expression tree is VERBATIM the R9/R11 scalar form (selects + trans per
// component; fma/mul/add shapes unchanged → bit-identical per element).
// The razor-edge |h_diff|>pi pixel sees the exact same float sequence.
// ============================================================================

__device__ __forceinline__ v2 vatan2(v2 y, v2 x) {
    v2 ax, ay; ax.x = fabsf(x.x); ax.y = fabsf(x.y); ay.x = fabsf(y.x); ay.y = fabsf(y.y);
    v2 mx, mn;
    mx.x = fmaxf(ax.x, ay.x); mx.y = fmaxf(ax.y, ay.y);
    mn.x = fminf(ax.x, ay.x); mn.y = fminf(ax.y, ay.y);
    v2 r = mn * vrcp(mx);
    v2 s = r * r;
    v2 p = vfma(s, V(-0.01172120f), V(0.05265332f));
    p = vfma(s, p, V(-0.11643287f));
    p = vfma(s, p, V( 0.19354346f));
    p = vfma(s, p, V(-0.33262347f));
    p = vfma(s, p, V( 0.99997726f));
    v2 th = r * p;
    th.x = (ay.x > ax.x)   ? (1.57079632679f - th.x) : th.x;
    th.y = (ay.y > ax.y)   ? (1.57079632679f - th.y) : th.y;
    th.x = (x.x < 0.0f)    ? (PI_F - th.x)           : th.x;
    th.y = (x.y < 0.0f)    ? (PI_F - th.y)           : th.y;
    th.x = (y.x < 0.0f)    ? -th.x                   : th.x;
    th.y = (y.y < 0.0f)    ? -th.y                   : th.y;
    th.x = (mx.x == 0.0f)  ? 0.0f                    : th.x;   // atan2(0,0) = 0
    th.y = (mx.y == 0.0f)  ? 0.0f                    : th.y;
    return th;
}

__device__ __forceinline__ v2 vsrgb_lin(v2 c) {
    v2 u = vfma(c, V(1.0f / 1.055f), V(0.055f / 1.055f));
    v2 p; p.x = fexp2(2.4f * flog2(u.x)); p.y = fexp2(2.4f * flog2(u.y));
    v2 l = c * (1.0f / 12.92f);
    v2 r;
    r.x = (c.x > 0.04045f) ? p.x : l.x;
    r.y = (c.y > 0.04045f) ? p.y : l.y;
    return r;
}

__device__ __forceinline__ v2 vlabf(v2 t) {
    v2 cr; cr.x = fexp2(0.333333333333f * flog2(t.x)); cr.y = fexp2(0.333333333333f * flog2(t.y));
    v2 ln = vfma(V(7.787f), t, V(4.0f / 29.0f));
    v2 r;
    r.x = (t.x > 0.008856f) ? cr.x : ln.x;
    r.y = (t.y > 0.008856f) ? cr.y : ln.y;
    return r;
}

__device__ __forceinline__ void vrgb2lab(v2 r, v2 g, v2 b,
                                         v2& L, v2& A, v2& B) {
    r = vsrgb_lin(r); g = vsrgb_lin(g); b = vsrgb_lin(b);
    v2 xn = 0.4339463f * r + 0.3762135f * g + 0.1898252f * b;
    v2 yn = 0.212671f  * r + 0.71516f   * g + 0.072169f  * b;
    v2 zn = 0.0177566f * r + 0.1094694f * g + 0.8727056f * b;
    v2 fx = vlabf(xn);
    v2 fy = vlabf(yn);
    v2 fz = vlabf(zn);
    L = vfma(V(116.0f), fy, V(-16.0f));
    A = 500.0f * (fx - fy);
    B = 200.0f * (fy - fz);
}

// Scalar hue tail — VERBATIM branch semantics from the R9/R11 kernel.
__device__ __forceinline__ void hue_tail(float h1, float h2, float C1p, float C2p,
                                         float& dHt, float& Hb) {
    float h_diff = h2 - h1;
    float h_sum  = h1 + h2;
    float CC = C1p * C2p;
    bool cc0 = (CC == 0.0f);

    float dH = (h_diff > PI_F) ? (h_diff - TWO_PI_F)
             : ((h_diff < -PI_F) ? (h_diff + TWO_PI_F) : h_diff);
    if (cc0) dH = 0.0f;
    dHt = 2.0f * fsqrt(CC) * fsin(0.5f * dH);

    bool mask = (!cc0) && (fabsf(h_diff) > PI_F);
    float Hbar = h_sum;
    if (mask) Hbar = (h_sum < TWO_PI_F) ? (h_sum + TWO_PI_F) : (h_sum - TWO_PI_F);
    if (cc0)  Hbar = h_sum * 2.0f;
    Hb = 0.5f * Hbar;
}

// ============================================================================
// Fused single-chain pipeline (upstream + downstream) — VERBATIM R4 numerics.
// ============================================================================

__device__ __forceinline__ v2 chain_v2(v2 r1, v2 g1, v2 bl1,
                                       v2 r2, v2 g2, v2 bl2) {
    v2 L1, A1, B1, L2, A2, B2;
    vrgb2lab(r1, g1, bl1, L1, A1, B1);
    vrgb2lab(r2, g2, bl2, L2, A2, B2);

    const float P25_7 = 6103515625.0f;  // 25^7

    v2 C1 = vsqrt(vfma(A1, A1, B1 * B1));
    v2 C2 = vsqrt(vfma(A2, A2, B2 * B2));
    v2 Cbar = 0.5f * (C1 + C2);
    v2 cb2 = Cbar * Cbar;
    v2 c7 = cb2 * cb2 * cb2 * Cbar;
    v2 G = vfma(-0.5f * c7, vrsq(vfma(c7, c7, vfma(V(P25_7), c7, V(1e-20f)))), V(0.5f));
    v2 s = V(1.0f) + G;
    v2 a1p = A1 * s, a2p = A2 * s;
    v2 C1p = vsqrt(vfma(a1p, a1p, B1 * B1));
    v2 C2p = vsqrt(vfma(a2p, a2p, B2 * B2));

    v2 h1 = vatan2(B1, a1p);
    h1.x = (h1.x < 0.0f) ? h1.x + TWO_PI_F : h1.x;
    h1.y = (h1.y < 0.0f) ? h1.y + TWO_PI_F : h1.y;
    v2 h2 = vatan2(B2, a2p);
    h2.x = (h2.x < 0.0f) ? h2.x + TWO_PI_F : h2.x;
    h2.y = (h2.y < 0.0f) ? h2.y + TWO_PI_F : h2.y;

    v2 dHt, Hb;
    {
        float d0, b0, d1, b1v;
        hue_tail(h1.x, h2.x, C1p.x, C2p.x, d0, b0);
        hue_tail(h1.y, h2.y, C1p.y, C2p.y, d1, b1v);
        dHt.x = d0; dHt.y = d1; Hb.x = b0; Hb.y = b1v;
    }

    // ---- downstream (smooth; packed IEEE elementwise) ----
    v2 Lbar = (L1 + L2) * 0.5f;
    v2 lt = Lbar - V(50.0f);
    v2 tmp = lt * lt;
    v2 SL = vfma(tmp * 0.015f, vrsq(V(20.0f) + tmp), V(1.0f));

    v2 Cbarp = (C1p + C2p) * 0.5f;
    v2 SC = vfma(V(0.045f), Cbarp, V(1.0f));

    v2 ch = vcosr(Hb);
    v2 sh = vsinr(Hb);
    v2 c2 = vfma(ch * 2.0f, ch, V(-1.0f));
    v2 s2 = sh * ch * 2.0f;
    v2 c3 = ch * c2 - sh * s2;
    v2 s3 = sh * c2 + ch * s2;
    v2 c4 = vfma(c2 * 2.0f, c2, V(-1.0f));
    v2 s4 = s2 * c2 * 2.0f;
    v2 T1 = vfma(ch, V(0.86602540378f), sh * 0.5f);              // cos(H-30deg)
    v2 T3 = vfma(c3, V(0.99452189536f), s3 * -0.10452846327f);   // cos(3H+6deg)
    v2 T4 = vfma(c4, V(0.45399049974f), s4 * 0.89100652419f);    // cos(4H-63deg)
    v2 T = V(1.0f) - T1 * 0.17f + c2 * 0.24f + T3 * 0.32f - T4 * 0.20f;
    v2 SH = vfma(Cbarp * 0.015f, T, V(1.0f));

    v2 PQ  = SC * SH;
    v2 inv = vrcp(SL * PQ);
    v2 L_term = (L2 - L1) * PQ * inv;
    v2 C_term = (C2p - C1p) * (SL * SH) * inv;
    v2 H_term = dHt * (SL * SC) * inv;

    v2 cp2 = Cbarp * Cbarp;
    v2 c7p = cp2 * cp2 * cp2 * Cbarp;
    v2 Rc = c7p * 2.0f * vrsq(vfma(c7p, c7p, vfma(V(P25_7), c7p, V(1e-20f))));

    v2 hd = vfma(Hb, V(2.752769787f), V(-13.2123465f));
    v2 vv = vexp2(-(hd * hd)) * 1.04719755119f;          // = 2*dtheta in (0, pi/3]
    v2 w  = vv * vv;
    v2 sp = vfma(w, V(-1.0f / 5040.0f), V(1.0f / 120.0f));
    sp = vfma(w, sp, V(-1.0f / 6.0f));
    sp = vfma(w, sp, V(1.0f));
    v2 sin2dt = vv * sp;
    v2 R_term = -(sin2dt * Rc * C_term * H_term);

    v2 dE2 = vfma(L_term, L_term, vfma(C_term, C_term, vfma(H_term, H_term, R_term)));
    return vsqrt(vmax0(dE2)) * 0.01f;
}

// ============================================================================
// R7: grid-stride ×4 with one-iteration-ahead prefetch. 2048 blocks × 256
// threads = exactly 8 blocks/CU; each thread processes 4 float2 work-items
// (stride 524288) with the next iteration's 6 loads issued BEFORE the current
// iteration's compute — hides the ~800cy HBM latency under ~2500cy of ALU,
// and amortizes wave cold-start 4×. Numerics identical to R4 (passing).
// ============================================================================

__global__ __launch_bounds__(256) void ciede_kernel(
    const float* __restrict__ img1, const float* __restrict__ img2,
    float* __restrict__ out, int n2_total) {
    const int PLANE2 = 131072;              // 512*512/2  (float2 per plane)
    const int STRIDE = 524288;              // 2048 blocks * 256 threads
    int tid = blockIdx.x * 256 + threadIdx.x;

    float2 r1a, g1a, b1a, r2a, g2a, b2a;    // current iteration's data
    float2 r1b, g1b, b1b, r2b, g2b, b2b;    // prefetched next iteration

    // prologue: load iteration 0
    {
        int idx = tid;
        int n = idx >> 17;
        int j = idx & (PLANE2 - 1);
        const float2* p1 = reinterpret_cast<const float2*>(img1) + (size_t)n * 3 * PLANE2;
        const float2* p2 = reinterpret_cast<const float2*>(img2) + (size_t)n * 3 * PLANE2;
        r1a = p1[j]; g1a = p1[j + PLANE2]; b1a = p1[j + 2 * PLANE2];
        r2a = p2[j]; g2a = p2[j + PLANE2]; b2a = p2[j + 2 * PLANE2];
    }

    #pragma unroll
    for (int i = 0; i < 4; ++i) {
        // issue next iteration's loads before this iteration's compute
        if (i < 3) {
            int idx = tid + (i + 1) * STRIDE;
            int n = idx >> 17;
            int j = idx & (PLANE2 - 1);
            const float2* p1 = reinterpret_cast<const float2*>(img1) + (size_t)n * 3 * PLANE2;
            const float2* p2 = reinterpret_cast<const float2*>(img2) + (size_t)n * 3 * PLANE2;
            r1b = p1[j]; g1b = p1[j + PLANE2]; b1b = p1[j + 2 * PLANE2];
            r2b = p2[j]; g2b = p2[j + PLANE2]; b2b = p2[j + 2 * PLANE2];
        }

        v2 o = chain_v2(V2(r1a.x, r1a.y), V2(g1a.x, g1a.y), V2(b1a.x, b1a.y),
                        V2(r2a.x, r2a.y), V2(g2a.x, g2a.y), V2(b2a.x, b2a.y));

        float2 ov; ov.x = o.x; ov.y = o.y;
        reinterpret_cast<float2*>(out)[tid + i * STRIDE] = ov;

        // rotate prefetch -> current (static, fully unrolled: stays in regs)
        r1a = r1b; g1a = g1b; b1a = b1b;
        r2a = r2b; g2a = g2b; b2a = b2b;
    }
}

extern "C" void kernel_launch(void* const* d_in, const int* in_sizes, int n_in,
                              void* d_out, int out_size, void* d_ws, size_t ws_size,
                              hipStream_t stream) {
    const float* img1 = (const float*)d_in[0];
    const float* img2 = (const float*)d_in[1];
    float* out = (float*)d_out;

    int n2 = out_size / 2;           // 2,097,152 float2 work-items
    int grid = 2048;                 // 2048*256*4 == n2 exactly; 8 blocks/CU
    ciede_kernel<<<grid, 256, 0, stream>>>(img1, img2, out, n2);
}

// Round 8
// 127.305 us; speedup vs baseline: 1.0382x; 1.0382x over previous
//
#include <hip/hip_runtime.h>
#include <math.h>

#define PI_F      3.14159265358979323846f
#define TWO_PI_F  6.28318530717958647692f
#define INV_2PI_F 0.15915494309189533577f

typedef float v2 __attribute__((ext_vector_type(2)));

// ---- scalar raw-instruction helpers ----
__device__ __forceinline__ float fsqrt(float x)  { return __builtin_amdgcn_sqrtf(x); }
__device__ __forceinline__ float frcp(float x)   { return __builtin_amdgcn_rcpf(x); }
__device__ __forceinline__ float frsq(float x)   { return __builtin_amdgcn_rsqf(x); }
__device__ __forceinline__ float fexp2(float x)  { return __builtin_amdgcn_exp2f(x); }
__device__ __forceinline__ float flog2(float x)  { return __builtin_amdgcn_logf(x); }
__device__ __forceinline__ float fsin(float x)   { return __builtin_amdgcn_sinf(x * INV_2PI_F); }
__device__ __forceinline__ float fcos(float x)   { return __builtin_amdgcn_cosf(x * INV_2PI_F); }

// ---- v2 helpers: elementwise; trans ops stay scalar per component ----
__device__ __forceinline__ v2 V(float s){ v2 r; r.x = s; r.y = s; return r; }
__device__ __forceinline__ v2 V2(float a, float b){ v2 r; r.x = a; r.y = b; return r; }
#if __has_builtin(__builtin_elementwise_fma)
__device__ __forceinline__ v2 vfma(v2 a, v2 b, v2 c){ return __builtin_elementwise_fma(a, b, c); }
#else
__device__ __forceinline__ v2 vfma(v2 a, v2 b, v2 c){ v2 r; r.x=__fmaf_rn(a.x,b.x,c.x); r.y=__fmaf_rn(a.y,b.y,c.y); return r; }
#endif
__device__ __forceinline__ v2 vmax0(v2 a){ v2 r; r.x=fmaxf(a.x,0.0f); r.y=fmaxf(a.y,0.0f); return r; }
__device__ __forceinline__ v2 vsqrt(v2 x){ v2 r; r.x=fsqrt(x.x); r.y=fsqrt(x.y); return r; }
__device__ __forceinline__ v2 vrcp (v2 x){ v2 r; r.x=frcp(x.x);  r.y=frcp(x.y);  return r; }
__device__ __forceinline__ v2 vrsq (v2 x){ v2 r; r.x=frsq(x.x);  r.y=frsq(x.y);  return r; }
__device__ __forceinline__ v2 vexp2(v2 x){ v2 r; r.x=fexp2(x.x); r.y=fexp2(x.y); return r; }
__device__ __forceinline__ v2 vsinr(v2 x){ v2 r; r.x=fsin(x.x); r.y=fsin(x.y); return r; }
__device__ __forceinline__ v2 vcosr(v2 x){ v2 r; r.x=fcos(x.x); r.y=fcos(x.y); return r; }

// ============================================================================
// UPSTREAM — PACKED v2 (compiler-vectorized; NO inline asm). Every per-element
// expression tree is VERBATIM the R9/R11 scalar form (selects + trans per
// component; fma/mul/add shapes unchanged → bit-identical per element).
// Verified passing in R4 with absmax 0.0078125. DO NOT touch numerics:
// a razor-edge |h_diff|>pi pixel flips under sub-ulp perturbation.
// ============================================================================

__device__ __forceinline__ v2 vatan2(v2 y, v2 x) {
    v2 ax, ay; ax.x = fabsf(x.x); ax.y = fabsf(x.y); ay.x = fabsf(y.x); ay.y = fabsf(y.y);
    v2 mx, mn;
    mx.x = fmaxf(ax.x, ay.x); mx.y = fmaxf(ax.y, ay.y);
    mn.x = fminf(ax.x, ay.x); mn.y = fminf(ax.y, ay.y);
    v2 r = mn * vrcp(mx);
    v2 s = r * r;
    v2 p = vfma(s, V(-0.01172120f), V(0.05265332f));
    p = vfma(s, p, V(-0.11643287f));
    p = vfma(s, p, V( 0.19354346f));
    p = vfma(s, p, V(-0.33262347f));
    p = vfma(s, p, V( 0.99997726f));
    v2 th = r * p;
    th.x = (ay.x > ax.x)   ? (1.57079632679f - th.x) : th.x;
    th.y = (ay.y > ax.y)   ? (1.57079632679f - th.y) : th.y;
    th.x = (x.x < 0.0f)    ? (PI_F - th.x)           : th.x;
    th.y = (x.y < 0.0f)    ? (PI_F - th.y)           : th.y;
    th.x = (y.x < 0.0f)    ? -th.x                   : th.x;
    th.y = (y.y < 0.0f)    ? -th.y                   : th.y;
    th.x = (mx.x == 0.0f)  ? 0.0f                    : th.x;   // atan2(0,0) = 0
    th.y = (mx.y == 0.0f)  ? 0.0f                    : th.y;
    return th;
}

__device__ __forceinline__ v2 vsrgb_lin(v2 c) {
    v2 u = vfma(c, V(1.0f / 1.055f), V(0.055f / 1.055f));
    v2 p; p.x = fexp2(2.4f * flog2(u.x)); p.y = fexp2(2.4f * flog2(u.y));
    v2 l = c * (1.0f / 12.92f);
    v2 r;
    r.x = (c.x > 0.04045f) ? p.x : l.x;
    r.y = (c.y > 0.04045f) ? p.y : l.y;
    return r;
}

__device__ __forceinline__ v2 vlabf(v2 t) {
    v2 cr; cr.x = fexp2(0.333333333333f * flog2(t.x)); cr.y = fexp2(0.333333333333f * flog2(t.y));
    v2 ln = vfma(V(7.787f), t, V(4.0f / 29.0f));
    v2 r;
    r.x = (t.x > 0.008856f) ? cr.x : ln.x;
    r.y = (t.y > 0.008856f) ? cr.y : ln.y;
    return r;
}

__device__ __forceinline__ void vrgb2lab(v2 r, v2 g, v2 b,
                                         v2& L, v2& A, v2& B) {
    r = vsrgb_lin(r); g = vsrgb_lin(g); b = vsrgb_lin(b);
    v2 xn = 0.4339463f * r + 0.3762135f * g + 0.1898252f * b;
    v2 yn = 0.212671f  * r + 0.71516f   * g + 0.072169f  * b;
    v2 zn = 0.0177566f * r + 0.1094694f * g + 0.8727056f * b;
    v2 fx = vlabf(xn);
    v2 fy = vlabf(yn);
    v2 fz = vlabf(zn);
    L = vfma(V(116.0f), fy, V(-16.0f));
    A = 500.0f * (fx - fy);
    B = 200.0f * (fy - fz);
}

// Scalar hue tail — VERBATIM branch semantics from the R9/R11 kernel.
__device__ __forceinline__ void hue_tail(float h1, float h2, float C1p, float C2p,
                                         float& dHt, float& Hb) {
    float h_diff = h2 - h1;
    float h_sum  = h1 + h2;
    float CC = C1p * C2p;
    bool cc0 = (CC == 0.0f);

    float dH = (h_diff > PI_F) ? (h_diff - TWO_PI_F)
             : ((h_diff < -PI_F) ? (h_diff + TWO_PI_F) : h_diff);
    if (cc0) dH = 0.0f;
    dHt = 2.0f * fsqrt(CC) * fsin(0.5f * dH);

    bool mask = (!cc0) && (fabsf(h_diff) > PI_F);
    float Hbar = h_sum;
    if (mask) Hbar = (h_sum < TWO_PI_F) ? (h_sum + TWO_PI_F) : (h_sum - TWO_PI_F);
    if (cc0)  Hbar = h_sum * 2.0f;
    Hb = 0.5f * Hbar;
}

// ============================================================================
// Fused single-chain pipeline (upstream + downstream) — VERBATIM R4 numerics.
// ============================================================================

__device__ __forceinline__ v2 chain_v2(v2 r1, v2 g1, v2 bl1,
                                       v2 r2, v2 g2, v2 bl2) {
    v2 L1, A1, B1, L2, A2, B2;
    vrgb2lab(r1, g1, bl1, L1, A1, B1);
    vrgb2lab(r2, g2, bl2, L2, A2, B2);

    const float P25_7 = 6103515625.0f;  // 25^7

    v2 C1 = vsqrt(vfma(A1, A1, B1 * B1));
    v2 C2 = vsqrt(vfma(A2, A2, B2 * B2));
    v2 Cbar = 0.5f * (C1 + C2);
    v2 cb2 = Cbar * Cbar;
    v2 c7 = cb2 * cb2 * cb2 * Cbar;
    v2 G = vfma(-0.5f * c7, vrsq(vfma(c7, c7, vfma(V(P25_7), c7, V(1e-20f)))), V(0.5f));
    v2 s = V(1.0f) + G;
    v2 a1p = A1 * s, a2p = A2 * s;
    v2 C1p = vsqrt(vfma(a1p, a1p, B1 * B1));
    v2 C2p = vsqrt(vfma(a2p, a2p, B2 * B2));

    v2 h1 = vatan2(B1, a1p);
    h1.x = (h1.x < 0.0f) ? h1.x + TWO_PI_F : h1.x;
    h1.y = (h1.y < 0.0f) ? h1.y + TWO_PI_F : h1.y;
    v2 h2 = vatan2(B2, a2p);
    h2.x = (h2.x < 0.0f) ? h2.x + TWO_PI_F : h2.x;
    h2.y = (h2.y < 0.0f) ? h2.y + TWO_PI_F : h2.y;

    v2 dHt, Hb;
    {
        float d0, b0, d1, b1v;
        hue_tail(h1.x, h2.x, C1p.x, C2p.x, d0, b0);
        hue_tail(h1.y, h2.y, C1p.y, C2p.y, d1, b1v);
        dHt.x = d0; dHt.y = d1; Hb.x = b0; Hb.y = b1v;
    }

    // ---- downstream (smooth; packed IEEE elementwise) ----
    v2 Lbar = (L1 + L2) * 0.5f;
    v2 lt = Lbar - V(50.0f);
    v2 tmp = lt * lt;
    v2 SL = vfma(tmp * 0.015f, vrsq(V(20.0f) + tmp), V(1.0f));

    v2 Cbarp = (C1p + C2p) * 0.5f;
    v2 SC = vfma(V(0.045f), Cbarp, V(1.0f));

    v2 ch = vcosr(Hb);
    v2 sh = vsinr(Hb);
    v2 c2 = vfma(ch * 2.0f, ch, V(-1.0f));
    v2 s2 = sh * ch * 2.0f;
    v2 c3 = ch * c2 - sh * s2;
    v2 s3 = sh * c2 + ch * s2;
    v2 c4 = vfma(c2 * 2.0f, c2, V(-1.0f));
    v2 s4 = s2 * c2 * 2.0f;
    v2 T1 = vfma(ch, V(0.86602540378f), sh * 0.5f);              // cos(H-30deg)
    v2 T3 = vfma(c3, V(0.99452189536f), s3 * -0.10452846327f);   // cos(3H+6deg)
    v2 T4 = vfma(c4, V(0.45399049974f), s4 * 0.89100652419f);    // cos(4H-63deg)
    v2 T = V(1.0f) - T1 * 0.17f + c2 * 0.24f + T3 * 0.32f - T4 * 0.20f;
    v2 SH = vfma(Cbarp * 0.015f, T, V(1.0f));

    v2 PQ  = SC * SH;
    v2 inv = vrcp(SL * PQ);
    v2 L_term = (L2 - L1) * PQ * inv;
    v2 C_term = (C2p - C1p) * (SL * SH) * inv;
    v2 H_term = dHt * (SL * SC) * inv;

    v2 cp2 = Cbarp * Cbarp;
    v2 c7p = cp2 * cp2 * cp2 * Cbarp;
    v2 Rc = c7p * 2.0f * vrsq(vfma(c7p, c7p, vfma(V(P25_7), c7p, V(1e-20f))));

    v2 hd = vfma(Hb, V(2.752769787f), V(-13.2123465f));
    v2 vv = vexp2(-(hd * hd)) * 1.04719755119f;          // = 2*dtheta in (0, pi/3]
    v2 w  = vv * vv;
    v2 sp = vfma(w, V(-1.0f / 5040.0f), V(1.0f / 120.0f));
    sp = vfma(w, sp, V(-1.0f / 6.0f));
    sp = vfma(w, sp, V(1.0f));
    v2 sin2dt = vv * sp;
    v2 R_term = -(sin2dt * Rc * C_term * H_term);

    v2 dE2 = vfma(L_term, L_term, vfma(C_term, C_term, vfma(H_term, H_term, R_term)));
    return vsqrt(vmax0(dE2)) * 0.01f;
}

// ============================================================================
// CLOSING CONFIG: 2 px/thread (one packed chain) × 64-thread one-wave blocks
// — the best-measured geometry of the session (R0: dur_us 126.275). 32768
// independent blocks self-balance across CUs; minimal VGPR footprint.
// Session ledger (kernel time): all of {64t/256t blocks, 2/4 px per thread,
// chain interleave/serialize, launch-bounds caps, forced VOP3P, prefetch +
// grid-stride} land 40.4-44.4 µs. Issue-port arithmetic: VALUBusy ~55% +
// uncounted trans-pipe ~20% ≈ 75% port saturation; the remaining ~25% is
// cold-HBM latency (harness's 268 MB re-poison evicts LLC each iteration)
// + dispatch tail, resistant to all source-level scheduling levers.
// ============================================================================

__global__ __launch_bounds__(64) void ciede_kernel(
    const float* __restrict__ img1, const float* __restrict__ img2,
    float* __restrict__ out, int n2_total) {
    int idx = blockIdx.x * 64 + threadIdx.x;
    if (idx >= n2_total) return;

    const int PLANE2 = 131072;              // 512*512/2
    int n = idx >> 17;                      // batch index
    int j = idx & (PLANE2 - 1);             // float2 index within plane

    const float2* p1 = reinterpret_cast<const float2*>(img1) + (size_t)n * 3 * PLANE2;
    const float2* p2 = reinterpret_cast<const float2*>(img2) + (size_t)n * 3 * PLANE2;

    float2 r1 = p1[j], g1 = p1[j + PLANE2], b1 = p1[j + 2 * PLANE2];
    float2 r2 = p2[j], g2 = p2[j + PLANE2], b2 = p2[j + 2 * PLANE2];

    v2 o = chain_v2(V2(r1.x, r1.y), V2(g1.x, g1.y), V2(b1.x, b1.y),
                    V2(r2.x, r2.y), V2(g2.x, g2.y), V2(b2.x, b2.y));

    float2 ov; ov.x = o.x; ov.y = o.y;
    reinterpret_cast<float2*>(out)[idx] = ov;
}

extern "C" void kernel_launch(void* const* d_in, const int* in_sizes, int n_in,
                              void* d_out, int out_size, void* d_ws, size_t ws_size,
                              hipStream_t stream) {
    const float* img1 = (const float*)d_in[0];
    const float* img2 = (const float*)d_in[1];
    float* out = (float*)d_out;

    int n2 = out_size / 2;           // 2,097,152 float2 work-items
    int grid = (n2 + 63) / 64;       // 32768 one-wave blocks
    ciede_kernel<<<grid, 64, 0, stream>>>(img1, img2, out, n2);
}